// Round 1
// baseline (23928.606 us; speedup 1.0000x reference)
//
#include <hip/hip_runtime.h>
#include <hip/hip_bf16.h>
#include <stdint.h>

typedef __bf16 bf16_t;
typedef bf16_t bf16x8 __attribute__((ext_vector_type(8)));
typedef float f32x4 __attribute__((ext_vector_type(4)));

#define NB 8
#define NT 4096
#define ND 1024
#define NG 64     // recurrence workgroups
#define RPG 16    // output dims per WG
#define LSTR 1032 // padded LDS row stride (bf16 elems): 2064 B, 16B-aligned, 2-way banks max

__device__ __forceinline__ float fast_tanh(float p) {
  // 1 - 2/(e^{2p}+1); exact at +/-inf via expf saturation
  return 1.0f - 2.0f / (__expf(2.0f * p) + 1.0f);
}
__device__ __forceinline__ float silu_f(float v) {
  return v / (1.0f + __expf(-v));
}
__device__ __forceinline__ unsigned short f2bf(float f) {
  bf16_t h = (bf16_t)f;
  return __builtin_bit_cast(unsigned short, h);
}
__device__ __forceinline__ bf16x8 pack8(float4 a, float4 b) {
  bf16x8 v;
  v[0] = (bf16_t)a.x; v[1] = (bf16_t)a.y; v[2] = (bf16_t)a.z; v[3] = (bf16_t)a.w;
  v[4] = (bf16_t)b.x; v[5] = (bf16_t)b.y; v[6] = (bf16_t)b.z; v[7] = (bf16_t)b.w;
  return v;
}

// ---------------- GEMM: xw[b*T+t][e] = sum_d x[.][d] * Wx[e][d] + bias[e] ----------------
// 128x128 tile, BK=32, 4 waves (2x2 of 64x64), mfma 16x16x32 bf16, fp32->bf16 reg-staged.
__global__ __launch_bounds__(256) void gemm_xw(const float* __restrict__ x,
                                               const float* __restrict__ Wx,
                                               const float* __restrict__ bias,
                                               float* __restrict__ xw) {
  __shared__ bf16_t As[128][40]; // 80B row stride -> <=2-way bank conflicts
  __shared__ bf16_t Bs[128][40];
  const int tid = threadIdx.x;
  const int bm = blockIdx.x >> 3; // 256 m-tiles of 128 (M=32768)
  const int bn = blockIdx.x & 7;  // 8 n-tiles of 128 (N=1024)
  const int lane = tid & 63;
  const int w = tid >> 6;
  const int wm = (w >> 1) * 64;
  const int wn = (w & 1) * 64;
  const int fr = lane & 15;
  const int fg = lane >> 4;

  f32x4 zero4 = {0.f, 0.f, 0.f, 0.f};
  f32x4 acc[4][4];
#pragma unroll
  for (int i = 0; i < 4; ++i)
#pragma unroll
    for (int j = 0; j < 4; ++j) acc[i][j] = zero4;

  const int r = tid >> 1;
  const int sseg = (tid & 1) * 16;
  const float* ap = x + (size_t)(bm * 128 + r) * ND + sseg;
  const float* bp = Wx + (size_t)(bn * 128 + r) * ND + sseg;

  float4 a0 = *(const float4*)(ap + 0);
  float4 a1 = *(const float4*)(ap + 4);
  float4 a2 = *(const float4*)(ap + 8);
  float4 a3 = *(const float4*)(ap + 12);
  float4 b0 = *(const float4*)(bp + 0);
  float4 b1 = *(const float4*)(bp + 4);
  float4 b2 = *(const float4*)(bp + 8);
  float4 b3 = *(const float4*)(bp + 12);

  for (int kb = 0; kb < 32; ++kb) {
    __syncthreads(); // previous iteration's LDS reads done
    *(bf16x8*)&As[r][sseg] = pack8(a0, a1);
    *(bf16x8*)&As[r][sseg + 8] = pack8(a2, a3);
    *(bf16x8*)&Bs[r][sseg] = pack8(b0, b1);
    *(bf16x8*)&Bs[r][sseg + 8] = pack8(b2, b3);
    __syncthreads();
    if (kb < 31) { // prefetch next K-slab; latency hides under MFMA below
      const float* ap2 = ap + (kb + 1) * 32;
      const float* bp2 = bp + (kb + 1) * 32;
      a0 = *(const float4*)(ap2 + 0);
      a1 = *(const float4*)(ap2 + 4);
      a2 = *(const float4*)(ap2 + 8);
      a3 = *(const float4*)(ap2 + 12);
      b0 = *(const float4*)(bp2 + 0);
      b1 = *(const float4*)(bp2 + 4);
      b2 = *(const float4*)(bp2 + 8);
      b3 = *(const float4*)(bp2 + 12);
    }
    bf16x8 af[4], bfv[4];
#pragma unroll
    for (int mi = 0; mi < 4; ++mi) af[mi] = *(const bf16x8*)&As[wm + mi * 16 + fr][fg * 8];
#pragma unroll
    for (int ni = 0; ni < 4; ++ni) bfv[ni] = *(const bf16x8*)&Bs[wn + ni * 16 + fr][fg * 8];
#pragma unroll
    for (int mi = 0; mi < 4; ++mi)
#pragma unroll
      for (int ni = 0; ni < 4; ++ni)
        acc[mi][ni] = __builtin_amdgcn_mfma_f32_16x16x32_bf16(af[mi], bfv[ni], acc[mi][ni], 0, 0, 0);
  }

#pragma unroll
  for (int ni = 0; ni < 4; ++ni) {
    const int col = bn * 128 + wn + ni * 16 + fr;
    const float bb = bias[col];
#pragma unroll
    for (int mi = 0; mi < 4; ++mi) {
#pragma unroll
      for (int j = 0; j < 4; ++j) {
        const int row = bm * 128 + wm + mi * 16 + fg * 4 + j;
        xw[(size_t)row * ND + col] = acc[mi][ni][j] + bb;
      }
    }
  }
}

// ---------------- init: h_buf[0] = bf16(h0), flags = 0 ----------------
__global__ void init_state(const float* __restrict__ h0,
                           unsigned short* __restrict__ hbuf,
                           unsigned int* __restrict__ flags) {
  const int i = blockIdx.x * 256 + threadIdx.x; // 8192 threads
  hbuf[i] = f2bf(h0[i]);
  if (i < NG) flags[i] = 0u;
}

// ---------------- recurrence: persistent, 64 WGs, flag-barrier per step ----------------
__global__ __launch_bounds__(256) void recur(const float* __restrict__ x,
                                             const float* __restrict__ Wh,
                                             float* __restrict__ outp,
                                             unsigned int* __restrict__ flags,
                                             unsigned short* __restrict__ hbuf) {
  __shared__ bf16_t W_s[RPG][LSTR]; // 33 KB: 16 rows of W_h (bf16)
  __shared__ bf16_t h_s[9][LSTR];   // 18.6 KB: 8 batch rows + 1 zero row (pads M to 16)
  __shared__ float cpart[4][16][18]; // per-wave partial C tiles

  const int tid = threadIdx.x;
  const int wg = blockIdx.x;
  const int lane = tid & 63;
  const int w = tid >> 6;
  const int fr = lane & 15;
  const int fg = lane >> 4;
  const int hrow = (fr < 8) ? fr : 8; // batches 8..15 read the zero row (broadcast)

  { // load W_h rows [wg*16, wg*16+16) as bf16 into LDS
    const int rr = tid >> 4;
    const int c0 = (tid & 15) * 64;
    const float* wp = Wh + (size_t)(wg * RPG + rr) * ND + c0;
#pragma unroll
    for (int c = 0; c < 64; c += 8) {
      float4 v0 = *(const float4*)(wp + c);
      float4 v1 = *(const float4*)(wp + c + 4);
      *(bf16x8*)&W_s[rr][c0 + c] = pack8(v0, v1);
    }
  }
  if (tid < 128) { // zero h_s row 8 once (never rewritten)
    *(uint4*)&h_s[8][tid * 8] = make_uint4(0u, 0u, 0u, 0u);
  }

  for (int t = 0; t < NT; ++t) {
    float2 xw2 = {0.f, 0.f}, x2 = {0.f, 0.f};
    if (tid < 64) {
      const int b = tid >> 3;
      const int ep = tid & 7;
      const size_t idx = ((size_t)b * NT + t) * ND + wg * RPG + ep * 2;
      xw2 = *(const float2*)&outp[idx]; // xw staged in d_out by gemm_xw
      x2 = *(const float2*)&x[idx];
      if (t > 0) { // wait until every WG finished step t-1
        unsigned int v;
        do {
          v = __hip_atomic_load(&flags[lane], __ATOMIC_RELAXED, __HIP_MEMORY_SCOPE_AGENT);
        } while (__any(v < (unsigned int)t));
      }
    }
    __syncthreads(); // waves 1-3 wait here while wave 0 polls
    __builtin_amdgcn_fence(__ATOMIC_ACQUIRE, "agent");
    { // stage h_prev (8 x 1024 bf16 = 16 KB) into LDS
      const uint4* src = (const uint4*)(hbuf + (size_t)(t & 1) * (NB * ND));
#pragma unroll
      for (int q = 0; q < 4; ++q) {
        const int i = q * 256 + tid;
        const uint4 v = src[i];
        const int brow = i >> 7;
        const int col = (i & 127) * 8;
        *(bf16x8*)&h_s[brow][col] = __builtin_bit_cast(bf16x8, v);
      }
    }
    __syncthreads();
    { // wave w: K in [w*256, w*256+256), one 16x16 tile (M=batch, N=e)
      f32x4 acc = {0.f, 0.f, 0.f, 0.f};
      const int kb0 = w * 256 + fg * 8;
#pragma unroll
      for (int c = 0; c < 8; ++c) {
        const int k = kb0 + c * 32;
        bf16x8 av = *(const bf16x8*)&h_s[hrow][k]; // A[m=batch][k]
        bf16x8 bv = *(const bf16x8*)&W_s[fr][k];   // B[k][n=e] = Wh[e][k]
        acc = __builtin_amdgcn_mfma_f32_16x16x32_bf16(av, bv, acc, 0, 0, 0);
      }
#pragma unroll
      for (int j = 0; j < 4; ++j) cpart[w][fg * 4 + j][fr] = acc[j];
    }
    __syncthreads();
    if (tid < 64) { // reduce K-partials, tanh, gate, publish h
      const int b = tid >> 3;
      const int ep = tid & 7;
      const int e0 = ep * 2;
      float p0 = cpart[0][b][e0] + cpart[1][b][e0] + cpart[2][b][e0] + cpart[3][b][e0] + xw2.x;
      float p1 = cpart[0][b][e0 + 1] + cpart[1][b][e0 + 1] + cpart[2][b][e0 + 1] + cpart[3][b][e0 + 1] + xw2.y;
      const float hn0 = fast_tanh(p0);
      const float hn1 = fast_tanh(p1);
      const size_t idx = ((size_t)b * NT + t) * ND + wg * RPG + e0;
      float2 o;
      o.x = hn0 * silu_f(x2.x);
      o.y = hn1 * silu_f(x2.y);
      *(float2*)&outp[idx] = o; // overwrites the consumed xw slot
      const unsigned int hu = (unsigned int)f2bf(hn0) | ((unsigned int)f2bf(hn1) << 16);
      unsigned int* hnext = (unsigned int*)(hbuf + (size_t)((t + 1) & 1) * (NB * ND));
      __hip_atomic_store(&hnext[b * 512 + wg * 8 + ep], hu, __ATOMIC_RELAXED, __HIP_MEMORY_SCOPE_AGENT);
      if (t == NT - 1) {
        float2 hf;
        hf.x = hn0;
        hf.y = hn1;
        *(float2*)&outp[(size_t)NB * NT * ND + (size_t)b * ND + wg * RPG + e0] = hf;
      }
      __builtin_amdgcn_fence(__ATOMIC_RELEASE, "agent");
      if (tid == 0) {
        __hip_atomic_store(&flags[wg], (unsigned int)(t + 1), __ATOMIC_RELAXED, __HIP_MEMORY_SCOPE_AGENT);
      }
    }
  }
}

extern "C" void kernel_launch(void* const* d_in, const int* in_sizes, int n_in,
                              void* d_out, int out_size, void* d_ws, size_t ws_size,
                              hipStream_t stream) {
  (void)in_sizes; (void)n_in; (void)out_size; (void)ws_size;
  const float* x = (const float*)d_in[0];
  const float* h0 = (const float*)d_in[1];
  const float* Wx = (const float*)d_in[2];
  const float* Wh = (const float*)d_in[3];
  const float* bias = (const float*)d_in[4];
  float* outp = (float*)d_out;
  unsigned int* flags = (unsigned int*)d_ws;                          // 64 * u32
  unsigned short* hbuf = (unsigned short*)((char*)d_ws + 1024);      // [2][8][1024] bf16

  gemm_xw<<<dim3(2048), dim3(256), 0, stream>>>(x, Wx, bias, outp);
  init_state<<<dim3(32), dim3(256), 0, stream>>>(h0, hbuf, flags);
  recur<<<dim3(NG), dim3(256), 0, stream>>>(x, Wh, outp, flags, hbuf);
}

// Round 2
// 23407.594 us; speedup vs baseline: 1.0223x; 1.0223x over previous
//
#include <hip/hip_runtime.h>
#include <hip/hip_bf16.h>
#include <stdint.h>

typedef __bf16 bf16_t;
typedef bf16_t bf16x8 __attribute__((ext_vector_type(8)));
typedef float f32x4 __attribute__((ext_vector_type(4)));

#define NB 8
#define NT 4096
#define ND 1024
#define NG 64     // recurrence workgroups
#define RPG 16    // output dims per WG
#define LSTR 1032 // padded LDS row stride (bf16 elems)
#define NWORDS 4096 // tagged u64 words per step (= NB*ND/2)

__device__ __forceinline__ float fast_tanh(float p) {
  return 1.0f - 2.0f / (__expf(2.0f * p) + 1.0f);
}
__device__ __forceinline__ float silu_f(float v) {
  return v / (1.0f + __expf(-v));
}
__device__ __forceinline__ unsigned short f2bf(float f) {
  bf16_t h = (bf16_t)f;
  return __builtin_bit_cast(unsigned short, h);
}
__device__ __forceinline__ bf16x8 pack8(float4 a, float4 b) {
  bf16x8 v;
  v[0] = (bf16_t)a.x; v[1] = (bf16_t)a.y; v[2] = (bf16_t)a.z; v[3] = (bf16_t)a.w;
  v[4] = (bf16_t)b.x; v[5] = (bf16_t)b.y; v[6] = (bf16_t)b.z; v[7] = (bf16_t)b.w;
  return v;
}

// ---------------- GEMM: xw[b*T+t][e] = sum_d x[.][d] * Wx[e][d] + bias[e] ----------------
__global__ __launch_bounds__(256) void gemm_xw(const float* __restrict__ x,
                                               const float* __restrict__ Wx,
                                               const float* __restrict__ bias,
                                               float* __restrict__ xw) {
  __shared__ bf16_t As[128][40];
  __shared__ bf16_t Bs[128][40];
  const int tid = threadIdx.x;
  const int bm = blockIdx.x >> 3;
  const int bn = blockIdx.x & 7;
  const int lane = tid & 63;
  const int w = tid >> 6;
  const int wm = (w >> 1) * 64;
  const int wn = (w & 1) * 64;
  const int fr = lane & 15;
  const int fg = lane >> 4;

  f32x4 zero4 = {0.f, 0.f, 0.f, 0.f};
  f32x4 acc[4][4];
#pragma unroll
  for (int i = 0; i < 4; ++i)
#pragma unroll
    for (int j = 0; j < 4; ++j) acc[i][j] = zero4;

  const int r = tid >> 1;
  const int sseg = (tid & 1) * 16;
  const float* ap = x + (size_t)(bm * 128 + r) * ND + sseg;
  const float* bp = Wx + (size_t)(bn * 128 + r) * ND + sseg;

  float4 a0 = *(const float4*)(ap + 0);
  float4 a1 = *(const float4*)(ap + 4);
  float4 a2 = *(const float4*)(ap + 8);
  float4 a3 = *(const float4*)(ap + 12);
  float4 b0 = *(const float4*)(bp + 0);
  float4 b1 = *(const float4*)(bp + 4);
  float4 b2 = *(const float4*)(bp + 8);
  float4 b3 = *(const float4*)(bp + 12);

  for (int kb = 0; kb < 32; ++kb) {
    __syncthreads();
    *(bf16x8*)&As[r][sseg] = pack8(a0, a1);
    *(bf16x8*)&As[r][sseg + 8] = pack8(a2, a3);
    *(bf16x8*)&Bs[r][sseg] = pack8(b0, b1);
    *(bf16x8*)&Bs[r][sseg + 8] = pack8(b2, b3);
    __syncthreads();
    if (kb < 31) {
      const float* ap2 = ap + (kb + 1) * 32;
      const float* bp2 = bp + (kb + 1) * 32;
      a0 = *(const float4*)(ap2 + 0);
      a1 = *(const float4*)(ap2 + 4);
      a2 = *(const float4*)(ap2 + 8);
      a3 = *(const float4*)(ap2 + 12);
      b0 = *(const float4*)(bp2 + 0);
      b1 = *(const float4*)(bp2 + 4);
      b2 = *(const float4*)(bp2 + 8);
      b3 = *(const float4*)(bp2 + 12);
    }
    bf16x8 af[4], bfv[4];
#pragma unroll
    for (int mi = 0; mi < 4; ++mi) af[mi] = *(const bf16x8*)&As[wm + mi * 16 + fr][fg * 8];
#pragma unroll
    for (int ni = 0; ni < 4; ++ni) bfv[ni] = *(const bf16x8*)&Bs[wn + ni * 16 + fr][fg * 8];
#pragma unroll
    for (int mi = 0; mi < 4; ++mi)
#pragma unroll
      for (int ni = 0; ni < 4; ++ni)
        acc[mi][ni] = __builtin_amdgcn_mfma_f32_16x16x32_bf16(af[mi], bfv[ni], acc[mi][ni], 0, 0, 0);
  }

#pragma unroll
  for (int ni = 0; ni < 4; ++ni) {
    const int col = bn * 128 + wn + ni * 16 + fr;
    const float bb = bias[col];
#pragma unroll
    for (int mi = 0; mi < 4; ++mi) {
#pragma unroll
      for (int j = 0; j < 4; ++j) {
        const int row = bm * 128 + wm + mi * 16 + fg * 4 + j;
        xw[(size_t)row * ND + col] = acc[mi][ni][j] + bb;
      }
    }
  }
}

// ---------------- init: tagged buffer parity 0 = {tag 0, bf16(h0)} ----------------
__global__ void init_state(const float* __restrict__ h0,
                           unsigned long long* __restrict__ tbuf) {
  const int i = blockIdx.x * 256 + threadIdx.x; // 4096 threads, one u64 word each
  const int g = i >> 6;
  const int wd = i & 63;
  const int b = wd >> 3;
  const int ep = wd & 7;
  const int d0 = g * RPG + ep * 2;
  const float2 hv = *(const float2*)&h0[b * ND + d0];
  const unsigned hu = (unsigned)f2bf(hv.x) | ((unsigned)f2bf(hv.y) << 16);
  const unsigned long long pk = (unsigned long long)hu; // tag 0 in hi32
  __hip_atomic_store(&tbuf[i], pk, __ATOMIC_RELAXED, __HIP_MEMORY_SCOPE_AGENT);
}

// ---------------- recurrence: persistent, 64 WGs, self-tagged h exchange ----------------
__global__ __launch_bounds__(256) void recur(const float* __restrict__ x,
                                             const float* __restrict__ Wh,
                                             float* __restrict__ outp,
                                             unsigned long long* __restrict__ tbuf) {
  __shared__ bf16_t W_s[RPG][LSTR];  // 16 rows of W_h (bf16)
  __shared__ bf16_t h_s[9][LSTR];    // 8 batch rows + 1 zero row (pads M to 16)
  __shared__ float cpart[4][16][18]; // per-wave partial C tiles

  const int tid = threadIdx.x;
  const int wg = blockIdx.x;
  const int lane = tid & 63;
  const int w = tid >> 6;
  const int fr = lane & 15;
  const int fg = lane >> 4;
  const int hrow = (fr < 8) ? fr : 8;

  { // load W_h rows [wg*16, wg*16+16) as bf16 into LDS
    const int rr = tid >> 4;
    const int c0 = (tid & 15) * 64;
    const float* wp = Wh + (size_t)(wg * RPG + rr) * ND + c0;
#pragma unroll
    for (int c = 0; c < 64; c += 8) {
      float4 v0 = *(const float4*)(wp + c);
      float4 v1 = *(const float4*)(wp + c + 4);
      *(bf16x8*)&W_s[rr][c0 + c] = pack8(v0, v1);
    }
  }
  if (tid < 128) {
    *(uint4*)&h_s[8][tid * 8] = make_uint4(0u, 0u, 0u, 0u);
  }

  for (int t = 0; t < NT; ++t) {
    float2 xw2 = {0.f, 0.f}, x2 = {0.f, 0.f};
    if (tid < 64) { // prefetch this step's xw/x; latency hides under the poll
      const int b = tid >> 3;
      const int ep = tid & 7;
      const size_t idx = ((size_t)b * NT + t) * ND + wg * RPG + ep * 2;
      xw2 = *(const float2*)&outp[idx]; // xw staged in d_out by gemm_xw
      x2 = *(const float2*)&x[idx];
    }
    { // poll tagged h words; stage into LDS as they validate
      const unsigned long long* rbuf = tbuf + (size_t)(t & 1) * NWORDS;
      unsigned valid = 0;
      do {
#pragma unroll
        for (int s = 0; s < 16; ++s) {
          if (!(valid & (1u << s))) {
            const unsigned long long pk =
                __hip_atomic_load(&rbuf[s * 256 + tid], __ATOMIC_RELAXED, __HIP_MEMORY_SCOPE_AGENT);
            if ((unsigned)(pk >> 32) == (unsigned)t) {
              valid |= 1u << s;
              const int idx = s * 256 + tid;
              const int g = idx >> 6;
              const int wd = idx & 63;
              const int b = wd >> 3;
              const int ep = wd & 7;
              *(unsigned*)&h_s[b][g * RPG + ep * 2] = (unsigned)pk;
            }
          }
        }
      } while (valid != 0xffffu);
    }
    __syncthreads();
    { // wave w: K in [w*256, w*256+256), one 16x16 tile (M=batch, N=e)
      f32x4 acc = {0.f, 0.f, 0.f, 0.f};
      const int kb0 = w * 256 + fg * 8;
#pragma unroll
      for (int c = 0; c < 8; ++c) {
        const int k = kb0 + c * 32;
        bf16x8 av = *(const bf16x8*)&h_s[hrow][k];
        bf16x8 bv = *(const bf16x8*)&W_s[fr][k];
        acc = __builtin_amdgcn_mfma_f32_16x16x32_bf16(av, bv, acc, 0, 0, 0);
      }
#pragma unroll
      for (int j = 0; j < 4; ++j) cpart[w][fg * 4 + j][fr] = acc[j];
    }
    __syncthreads();
    if (tid < 64) { // reduce K-partials, tanh, gate, publish tagged h
      const int b = tid >> 3;
      const int ep = tid & 7;
      const int e0 = ep * 2;
      float p0 = cpart[0][b][e0] + cpart[1][b][e0] + cpart[2][b][e0] + cpart[3][b][e0] + xw2.x;
      float p1 = cpart[0][b][e0 + 1] + cpart[1][b][e0 + 1] + cpart[2][b][e0 + 1] + cpart[3][b][e0 + 1] + xw2.y;
      const float hn0 = fast_tanh(p0);
      const float hn1 = fast_tanh(p1);
      const size_t idx = ((size_t)b * NT + t) * ND + wg * RPG + e0;
      float2 o;
      o.x = hn0 * silu_f(x2.x);
      o.y = hn1 * silu_f(x2.y);
      *(float2*)&outp[idx] = o;
      const unsigned hu = (unsigned)f2bf(hn0) | ((unsigned)f2bf(hn1) << 16);
      const unsigned long long pk = (unsigned long long)hu | ((unsigned long long)(unsigned)(t + 1) << 32);
      unsigned long long* wb = tbuf + (size_t)((t + 1) & 1) * NWORDS;
      __hip_atomic_store(&wb[wg * 64 + tid], pk, __ATOMIC_RELAXED, __HIP_MEMORY_SCOPE_AGENT);
      if (t == NT - 1) {
        float2 hf;
        hf.x = hn0;
        hf.y = hn1;
        *(float2*)&outp[(size_t)NB * NT * ND + (size_t)b * ND + wg * RPG + e0] = hf;
      }
    }
  }
}

extern "C" void kernel_launch(void* const* d_in, const int* in_sizes, int n_in,
                              void* d_out, int out_size, void* d_ws, size_t ws_size,
                              hipStream_t stream) {
  (void)in_sizes; (void)n_in; (void)out_size; (void)ws_size;
  const float* x = (const float*)d_in[0];
  const float* h0 = (const float*)d_in[1];
  const float* Wx = (const float*)d_in[2];
  const float* Wh = (const float*)d_in[3];
  const float* bias = (const float*)d_in[4];
  float* outp = (float*)d_out;
  unsigned long long* tbuf = (unsigned long long*)d_ws; // [2][4096] tagged u64

  gemm_xw<<<dim3(2048), dim3(256), 0, stream>>>(x, Wx, bias, outp);
  init_state<<<dim3(16), dim3(256), 0, stream>>>(h0, tbuf);
  recur<<<dim3(NG), dim3(256), 0, stream>>>(x, Wh, outp, tbuf);
}

// Round 3
// 10042.952 us; speedup vs baseline: 2.3826x; 2.3307x over previous
//
#include <hip/hip_runtime.h>
#include <hip/hip_bf16.h>
#include <stdint.h>

typedef __bf16 bf16_t;
typedef bf16_t bf16x8 __attribute__((ext_vector_type(8)));
typedef float f32x4 __attribute__((ext_vector_type(4)));

#define NB 8
#define NT 4096
#define ND 1024
#define NG 64     // recurrence workgroups
#define RPG 16    // output dims per WG
#define LSTR 1032 // padded LDS row stride (bf16 elems)
#define NWORDS 4096 // tagged u64 words per step (= NB*ND/2)

__device__ __forceinline__ float fast_tanh(float p) {
  return 1.0f - 2.0f / (__expf(2.0f * p) + 1.0f);
}
__device__ __forceinline__ float silu_f(float v) {
  return v / (1.0f + __expf(-v));
}
__device__ __forceinline__ unsigned short f2bf(float f) {
  bf16_t h = (bf16_t)f;
  return __builtin_bit_cast(unsigned short, h);
}
__device__ __forceinline__ bf16x8 pack8(float4 a, float4 b) {
  bf16x8 v;
  v[0] = (bf16_t)a.x; v[1] = (bf16_t)a.y; v[2] = (bf16_t)a.z; v[3] = (bf16_t)a.w;
  v[4] = (bf16_t)b.x; v[5] = (bf16_t)b.y; v[6] = (bf16_t)b.z; v[7] = (bf16_t)b.w;
  return v;
}

// ---------------- GEMM: xw[b*T+t][e] = sum_d x[.][d] * Wx[e][d] + bias[e] ----------------
__global__ __launch_bounds__(256) void gemm_xw(const float* __restrict__ x,
                                               const float* __restrict__ Wx,
                                               const float* __restrict__ bias,
                                               float* __restrict__ xw) {
  __shared__ bf16_t As[128][40];
  __shared__ bf16_t Bs[128][40];
  const int tid = threadIdx.x;
  const int bm = blockIdx.x >> 3;
  const int bn = blockIdx.x & 7;
  const int lane = tid & 63;
  const int w = tid >> 6;
  const int wm = (w >> 1) * 64;
  const int wn = (w & 1) * 64;
  const int fr = lane & 15;
  const int fg = lane >> 4;

  f32x4 zero4 = {0.f, 0.f, 0.f, 0.f};
  f32x4 acc[4][4];
#pragma unroll
  for (int i = 0; i < 4; ++i)
#pragma unroll
    for (int j = 0; j < 4; ++j) acc[i][j] = zero4;

  const int r = tid >> 1;
  const int sseg = (tid & 1) * 16;
  const float* ap = x + (size_t)(bm * 128 + r) * ND + sseg;
  const float* bp = Wx + (size_t)(bn * 128 + r) * ND + sseg;

  float4 a0 = *(const float4*)(ap + 0);
  float4 a1 = *(const float4*)(ap + 4);
  float4 a2 = *(const float4*)(ap + 8);
  float4 a3 = *(const float4*)(ap + 12);
  float4 b0 = *(const float4*)(bp + 0);
  float4 b1 = *(const float4*)(bp + 4);
  float4 b2 = *(const float4*)(bp + 8);
  float4 b3 = *(const float4*)(bp + 12);

  for (int kb = 0; kb < 32; ++kb) {
    __syncthreads();
    *(bf16x8*)&As[r][sseg] = pack8(a0, a1);
    *(bf16x8*)&As[r][sseg + 8] = pack8(a2, a3);
    *(bf16x8*)&Bs[r][sseg] = pack8(b0, b1);
    *(bf16x8*)&Bs[r][sseg + 8] = pack8(b2, b3);
    __syncthreads();
    if (kb < 31) {
      const float* ap2 = ap + (kb + 1) * 32;
      const float* bp2 = bp + (kb + 1) * 32;
      a0 = *(const float4*)(ap2 + 0);
      a1 = *(const float4*)(ap2 + 4);
      a2 = *(const float4*)(ap2 + 8);
      a3 = *(const float4*)(ap2 + 12);
      b0 = *(const float4*)(bp2 + 0);
      b1 = *(const float4*)(bp2 + 4);
      b2 = *(const float4*)(bp2 + 8);
      b3 = *(const float4*)(bp2 + 12);
    }
    bf16x8 af[4], bfv[4];
#pragma unroll
    for (int mi = 0; mi < 4; ++mi) af[mi] = *(const bf16x8*)&As[wm + mi * 16 + fr][fg * 8];
#pragma unroll
    for (int ni = 0; ni < 4; ++ni) bfv[ni] = *(const bf16x8*)&Bs[wn + ni * 16 + fr][fg * 8];
#pragma unroll
    for (int mi = 0; mi < 4; ++mi)
#pragma unroll
      for (int ni = 0; ni < 4; ++ni)
        acc[mi][ni] = __builtin_amdgcn_mfma_f32_16x16x32_bf16(af[mi], bfv[ni], acc[mi][ni], 0, 0, 0);
  }

#pragma unroll
  for (int ni = 0; ni < 4; ++ni) {
    const int col = bn * 128 + wn + ni * 16 + fr;
    const float bb = bias[col];
#pragma unroll
    for (int mi = 0; mi < 4; ++mi) {
#pragma unroll
      for (int j = 0; j < 4; ++j) {
        const int row = bm * 128 + wm + mi * 16 + fg * 4 + j;
        xw[(size_t)row * ND + col] = acc[mi][ni][j] + bb;
      }
    }
  }
}

// ---------------- init: tagged buffer parity 0 = {tag 0, bf16(h0)} ----------------
__global__ void init_state(const float* __restrict__ h0,
                           unsigned long long* __restrict__ tbuf) {
  const int i = blockIdx.x * 256 + threadIdx.x; // 4096 threads, one u64 word each
  const int g = i >> 6;
  const int wd = i & 63;
  const int b = wd >> 3;
  const int ep = wd & 7;
  const int d0 = g * RPG + ep * 2;
  const float2 hv = *(const float2*)&h0[b * ND + d0];
  const unsigned hu = (unsigned)f2bf(hv.x) | ((unsigned)f2bf(hv.y) << 16);
  const unsigned long long pk = (unsigned long long)hu; // tag 0 in hi32
  __hip_atomic_store(&tbuf[i], pk, __ATOMIC_RELAXED, __HIP_MEMORY_SCOPE_AGENT);
}

// ---------------- recurrence: persistent, 64 WGs, self-tagged h exchange ----------------
__global__ __launch_bounds__(256) void recur(const float* __restrict__ x,
                                             const float* __restrict__ Wh,
                                             float* __restrict__ outp,
                                             unsigned long long* __restrict__ tbuf) {
  __shared__ bf16_t W_s[RPG][LSTR];  // 16 rows of W_h (bf16)
  __shared__ bf16_t h_s[9][LSTR];    // 8 batch rows + 1 zero row (pads M to 16)
  __shared__ float cpart[4][16][18]; // per-wave partial C tiles

  const int tid = threadIdx.x;
  const int wg = blockIdx.x;
  const int lane = tid & 63;
  const int w = tid >> 6;
  const int fr = lane & 15;
  const int fg = lane >> 4;
  const int hrow = (fr < 8) ? fr : 8;

  { // load W_h rows [wg*16, wg*16+16) as bf16 into LDS
    const int rr = tid >> 4;
    const int c0 = (tid & 15) * 64;
    const float* wp = Wh + (size_t)(wg * RPG + rr) * ND + c0;
#pragma unroll
    for (int c = 0; c < 64; c += 8) {
      float4 v0 = *(const float4*)(wp + c);
      float4 v1 = *(const float4*)(wp + c + 4);
      *(bf16x8*)&W_s[rr][c0 + c] = pack8(v0, v1);
    }
  }
  if (tid < 128) {
    *(uint4*)&h_s[8][tid * 8] = make_uint4(0u, 0u, 0u, 0u);
  }

  for (int t = 0; t < NT; ++t) {
    float2 xw2 = {0.f, 0.f}, x2 = {0.f, 0.f};
    if (tid < 64) { // prefetch this step's xw/x; latency hides under the poll
      const int b = tid >> 3;
      const int ep = tid & 7;
      const size_t idx = ((size_t)b * NT + t) * ND + wg * RPG + ep * 2;
      xw2 = *(const float2*)&outp[idx]; // xw staged in d_out by gemm_xw
      x2 = *(const float2*)&x[idx];
    }
    { // poll tagged h words: batch-issue all 16 loads, single wait, check tags
      const unsigned long long* rbuf = tbuf + (size_t)(t & 1) * NWORDS;
      unsigned long long pk[16];
      bool allv;
      do {
#pragma unroll
        for (int s = 0; s < 16; ++s)
          pk[s] = __hip_atomic_load(&rbuf[s * 256 + tid], __ATOMIC_RELAXED, __HIP_MEMORY_SCOPE_AGENT);
        allv = true;
#pragma unroll
        for (int s = 0; s < 16; ++s)
          allv &= ((unsigned)(pk[s] >> 32) == (unsigned)t);
      } while (!allv);
#pragma unroll
      for (int s = 0; s < 16; ++s) { // stage validated h into LDS
        const int idx = s * 256 + tid;
        const int g = idx >> 6;
        const int wd = idx & 63;
        const int b = wd >> 3;
        const int ep = wd & 7;
        *(unsigned*)&h_s[b][g * RPG + ep * 2] = (unsigned)pk[s];
      }
    }
    __syncthreads();
    { // wave w: K in [w*256, w*256+256), one 16x16 tile (M=batch, N=e)
      f32x4 acc = {0.f, 0.f, 0.f, 0.f};
      const int kb0 = w * 256 + fg * 8;
#pragma unroll
      for (int c = 0; c < 8; ++c) {
        const int k = kb0 + c * 32;
        bf16x8 av = *(const bf16x8*)&h_s[hrow][k];
        bf16x8 bv = *(const bf16x8*)&W_s[fr][k];
        acc = __builtin_amdgcn_mfma_f32_16x16x32_bf16(av, bv, acc, 0, 0, 0);
      }
#pragma unroll
      for (int j = 0; j < 4; ++j) cpart[w][fg * 4 + j][fr] = acc[j];
    }
    __syncthreads();
    if (tid < 64) { // reduce K-partials, tanh, gate, publish tagged h
      const int b = tid >> 3;
      const int ep = tid & 7;
      const int e0 = ep * 2;
      float p0 = cpart[0][b][e0] + cpart[1][b][e0] + cpart[2][b][e0] + cpart[3][b][e0] + xw2.x;
      float p1 = cpart[0][b][e0 + 1] + cpart[1][b][e0 + 1] + cpart[2][b][e0 + 1] + cpart[3][b][e0 + 1] + xw2.y;
      const float hn0 = fast_tanh(p0);
      const float hn1 = fast_tanh(p1);
      const size_t idx = ((size_t)b * NT + t) * ND + wg * RPG + e0;
      float2 o;
      o.x = hn0 * silu_f(x2.x);
      o.y = hn1 * silu_f(x2.y);
      *(float2*)&outp[idx] = o;
      const unsigned hu = (unsigned)f2bf(hn0) | ((unsigned)f2bf(hn1) << 16);
      const unsigned long long pk = (unsigned long long)hu | ((unsigned long long)(unsigned)(t + 1) << 32);
      unsigned long long* wb = tbuf + (size_t)((t + 1) & 1) * NWORDS;
      __hip_atomic_store(&wb[wg * 64 + tid], pk, __ATOMIC_RELAXED, __HIP_MEMORY_SCOPE_AGENT);
      if (t == NT - 1) {
        float2 hf;
        hf.x = hn0;
        hf.y = hn1;
        *(float2*)&outp[(size_t)NB * NT * ND + (size_t)b * ND + wg * RPG + e0] = hf;
      }
    }
  }
}

extern "C" void kernel_launch(void* const* d_in, const int* in_sizes, int n_in,
                              void* d_out, int out_size, void* d_ws, size_t ws_size,
                              hipStream_t stream) {
  (void)in_sizes; (void)n_in; (void)out_size; (void)ws_size;
  const float* x = (const float*)d_in[0];
  const float* h0 = (const float*)d_in[1];
  const float* Wx = (const float*)d_in[2];
  const float* Wh = (const float*)d_in[3];
  const float* bias = (const float*)d_in[4];
  float* outp = (float*)d_out;
  unsigned long long* tbuf = (unsigned long long*)d_ws; // [2][4096] tagged u64

  gemm_xw<<<dim3(2048), dim3(256), 0, stream>>>(x, Wx, bias, outp);
  init_state<<<dim3(16), dim3(256), 0, stream>>>(h0, tbuf);
  recur<<<dim3(NG), dim3(256), 0, stream>>>(x, Wh, outp, tbuf);
}

// Round 4
// 8085.685 us; speedup vs baseline: 2.9594x; 1.2421x over previous
//
#include <hip/hip_runtime.h>
#include <hip/hip_bf16.h>
#include <stdint.h>

typedef __bf16 bf16_t;
typedef bf16_t bf16x8 __attribute__((ext_vector_type(8)));
typedef float f32x4 __attribute__((ext_vector_type(4)));

#define NB 8
#define NT 4096
#define ND 1024
#define GPB 16      // WGs per batch group
#define EPW 64      // e-dims per WG
#define NWPG 512    // tagged u64 words per group (=ND/2)
#define WSTR 1032   // padded LDS row stride for W_s (bf16 elems)

__device__ __forceinline__ float fast_tanh(float p) {
  return 1.0f - 2.0f / (__expf(2.0f * p) + 1.0f);
}
__device__ __forceinline__ float silu_f(float v) {
  return v / (1.0f + __expf(-v));
}
__device__ __forceinline__ unsigned short f2bf(float f) {
  bf16_t h = (bf16_t)f;
  return __builtin_bit_cast(unsigned short, h);
}
__device__ __forceinline__ bf16x8 pack8(float4 a, float4 b) {
  bf16x8 v;
  v[0] = (bf16_t)a.x; v[1] = (bf16_t)a.y; v[2] = (bf16_t)a.z; v[3] = (bf16_t)a.w;
  v[4] = (bf16_t)b.x; v[5] = (bf16_t)b.y; v[6] = (bf16_t)b.z; v[7] = (bf16_t)b.w;
  return v;
}

// ---------------- GEMM: xw[b*T+t][e] = sum_d x[.][d] * Wx[e][d] + bias[e] ----------------
__global__ __launch_bounds__(256) void gemm_xw(const float* __restrict__ x,
                                               const float* __restrict__ Wx,
                                               const float* __restrict__ bias,
                                               float* __restrict__ xw) {
  __shared__ bf16_t As[128][40];
  __shared__ bf16_t Bs[128][40];
  const int tid = threadIdx.x;
  const int bm = blockIdx.x >> 3;
  const int bn = blockIdx.x & 7;
  const int lane = tid & 63;
  const int w = tid >> 6;
  const int wm = (w >> 1) * 64;
  const int wn = (w & 1) * 64;
  const int fr = lane & 15;
  const int fg = lane >> 4;

  f32x4 zero4 = {0.f, 0.f, 0.f, 0.f};
  f32x4 acc[4][4];
#pragma unroll
  for (int i = 0; i < 4; ++i)
#pragma unroll
    for (int j = 0; j < 4; ++j) acc[i][j] = zero4;

  const int r = tid >> 1;
  const int sseg = (tid & 1) * 16;
  const float* ap = x + (size_t)(bm * 128 + r) * ND + sseg;
  const float* bp = Wx + (size_t)(bn * 128 + r) * ND + sseg;

  float4 a0 = *(const float4*)(ap + 0);
  float4 a1 = *(const float4*)(ap + 4);
  float4 a2 = *(const float4*)(ap + 8);
  float4 a3 = *(const float4*)(ap + 12);
  float4 b0 = *(const float4*)(bp + 0);
  float4 b1 = *(const float4*)(bp + 4);
  float4 b2 = *(const float4*)(bp + 8);
  float4 b3 = *(const float4*)(bp + 12);

  for (int kb = 0; kb < 32; ++kb) {
    __syncthreads();
    *(bf16x8*)&As[r][sseg] = pack8(a0, a1);
    *(bf16x8*)&As[r][sseg + 8] = pack8(a2, a3);
    *(bf16x8*)&Bs[r][sseg] = pack8(b0, b1);
    *(bf16x8*)&Bs[r][sseg + 8] = pack8(b2, b3);
    __syncthreads();
    if (kb < 31) {
      const float* ap2 = ap + (kb + 1) * 32;
      const float* bp2 = bp + (kb + 1) * 32;
      a0 = *(const float4*)(ap2 + 0);
      a1 = *(const float4*)(ap2 + 4);
      a2 = *(const float4*)(ap2 + 8);
      a3 = *(const float4*)(ap2 + 12);
      b0 = *(const float4*)(bp2 + 0);
      b1 = *(const float4*)(bp2 + 4);
      b2 = *(const float4*)(bp2 + 8);
      b3 = *(const float4*)(bp2 + 12);
    }
    bf16x8 af[4], bfv[4];
#pragma unroll
    for (int mi = 0; mi < 4; ++mi) af[mi] = *(const bf16x8*)&As[wm + mi * 16 + fr][fg * 8];
#pragma unroll
    for (int ni = 0; ni < 4; ++ni) bfv[ni] = *(const bf16x8*)&Bs[wn + ni * 16 + fr][fg * 8];
#pragma unroll
    for (int mi = 0; mi < 4; ++mi)
#pragma unroll
      for (int ni = 0; ni < 4; ++ni)
        acc[mi][ni] = __builtin_amdgcn_mfma_f32_16x16x32_bf16(af[mi], bfv[ni], acc[mi][ni], 0, 0, 0);
  }

#pragma unroll
  for (int ni = 0; ni < 4; ++ni) {
    const int col = bn * 128 + wn + ni * 16 + fr;
    const float bb = bias[col];
#pragma unroll
    for (int mi = 0; mi < 4; ++mi) {
#pragma unroll
      for (int j = 0; j < 4; ++j) {
        const int row = bm * 128 + wm + mi * 16 + fg * 4 + j;
        xw[(size_t)row * ND + col] = acc[mi][ni][j] + bb;
      }
    }
  }
}

// ---------------- init: parity-0 tagged words = {tag 0, bf16(h0) pair} ----------------
// tbuf layout: [parity][batch][word j], word j = {tag(hi32), bf16 h[2j] | bf16 h[2j+1]<<16}
__global__ void init_state(const float* __restrict__ h0,
                           unsigned long long* __restrict__ tbuf) {
  const int i = blockIdx.x * 256 + threadIdx.x; // 4096 words
  const int b = i >> 9;
  const int j = i & 511;
  const float2 hv = *(const float2*)&h0[b * ND + 2 * j];
  const unsigned hu = (unsigned)f2bf(hv.x) | ((unsigned)f2bf(hv.y) << 16);
  __hip_atomic_store(&tbuf[i], (unsigned long long)hu, __ATOMIC_RELAXED, __HIP_MEMORY_SCOPE_AGENT);
}

// ---------------- recurrence: 8 independent batch groups x 16 WGs ----------------
// WG owns 64 e-dims of one batch; 4 waves x 16 e, K=1024 each; h is broadcast B-operand.
__global__ __launch_bounds__(256) void recur(const float* __restrict__ x,
                                             const float* __restrict__ Wh,
                                             float* __restrict__ outp,
                                             unsigned long long* __restrict__ tbuf) {
  __shared__ bf16_t W_s[EPW][WSTR]; // 132 KB: 64 rows of W_h (bf16)
  __shared__ bf16_t h_s[2][ND];     // 4 KB: double-buffered h for this batch

  const int tid = threadIdx.x;
  const int wg = blockIdx.x;
  const int b = wg >> 4;        // batch group
  const int wgl = wg & 15;      // WG within group
  const int e_base = wgl * EPW; // global e offset of this WG
  const int lane = tid & 63;
  const int w = tid >> 6;
  const int fr = lane & 15;
  const int fg = lane >> 4;
  const int e0 = e_base + w * 16 + fg * 4; // this lane's 4 e-dims (valid for fr==0 use)

  { // load W_h rows [e_base, e_base+64) as bf16 into LDS
    const int r = tid >> 2;
    const int c0 = (tid & 3) * 256;
    const float* wp = Wh + (size_t)(e_base + r) * ND + c0;
#pragma unroll
    for (int c = 0; c < 256; c += 8) {
      float4 v0 = *(const float4*)(wp + c);
      float4 v1 = *(const float4*)(wp + c + 4);
      *(bf16x8*)&W_s[r][c0 + c] = pack8(v0, v1);
    }
  }

  const bf16_t* wrow = &W_s[w * 16 + fr][0];
  unsigned long long* const gbase = tbuf + (size_t)b * NWPG;

  for (int t = 0; t < NT; ++t) {
    float4 xw4, xg4;
    if (fr == 0) { // prefetch this step's xw and gate input; hides under poll
      const size_t ix = ((size_t)b * NT + t) * ND + e0;
      xw4 = *(const float4*)&outp[ix]; // xw staged in d_out by gemm_xw
      xg4 = *(const float4*)&x[ix];
    }
    { // poll 2 tagged words, stage into h_s[t&1]
      const unsigned long long* rbuf = gbase + (size_t)(t & 1) * (NB * NWPG);
      unsigned long long w0, w1;
      for (;;) {
        w0 = __hip_atomic_load(&rbuf[2 * tid], __ATOMIC_RELAXED, __HIP_MEMORY_SCOPE_AGENT);
        w1 = __hip_atomic_load(&rbuf[2 * tid + 1], __ATOMIC_RELAXED, __HIP_MEMORY_SCOPE_AGENT);
        if (((unsigned)(w0 >> 32) == (unsigned)t) & ((unsigned)(w1 >> 32) == (unsigned)t)) break;
      }
      const unsigned long long hv = (w0 & 0xffffffffull) | (w1 << 32);
      *(unsigned long long*)&h_s[t & 1][4 * tid] = hv; // e = 4*tid .. 4*tid+3
    }
    __syncthreads(); // single barrier per step: stage complete -> MFMA may read
    const bf16_t* hp = &h_s[t & 1][0];
    f32x4 a0 = {0.f, 0.f, 0.f, 0.f}, a1 = a0, a2 = a0, a3 = a0;
#pragma unroll
    for (int cc = 0; cc < 8; ++cc) {
      const int k = cc * 128 + fg * 8;
      a0 = __builtin_amdgcn_mfma_f32_16x16x32_bf16(*(const bf16x8*)(wrow + k), *(const bf16x8*)(hp + k), a0, 0, 0, 0);
      a1 = __builtin_amdgcn_mfma_f32_16x16x32_bf16(*(const bf16x8*)(wrow + k + 32), *(const bf16x8*)(hp + k + 32), a1, 0, 0, 0);
      a2 = __builtin_amdgcn_mfma_f32_16x16x32_bf16(*(const bf16x8*)(wrow + k + 64), *(const bf16x8*)(hp + k + 64), a2, 0, 0, 0);
      a3 = __builtin_amdgcn_mfma_f32_16x16x32_bf16(*(const bf16x8*)(wrow + k + 96), *(const bf16x8*)(hp + k + 96), a3, 0, 0, 0);
    }
    const f32x4 as = (a0 + a1) + (a2 + a3); // C[m=fg*4+j][n] identical over n

    if (fr == 0) { // epilogue: tanh, publish (first!), gate, store
      const float h0v = fast_tanh(as[0] + xw4.x);
      const float h1v = fast_tanh(as[1] + xw4.y);
      const float h2v = fast_tanh(as[2] + xw4.z);
      const float h3v = fast_tanh(as[3] + xw4.w);
      const unsigned long long tag = (unsigned long long)(unsigned)(t + 1) << 32;
      const unsigned long long p0 =
          tag | (unsigned long long)((unsigned)f2bf(h0v) | ((unsigned)f2bf(h1v) << 16));
      const unsigned long long p1 =
          tag | (unsigned long long)((unsigned)f2bf(h2v) | ((unsigned)f2bf(h3v) << 16));
      unsigned long long* wb = gbase + (size_t)((t + 1) & 1) * (NB * NWPG);
      const int j0 = e0 >> 1;
      __hip_atomic_store(&wb[j0], p0, __ATOMIC_RELAXED, __HIP_MEMORY_SCOPE_AGENT);
      __hip_atomic_store(&wb[j0 + 1], p1, __ATOMIC_RELAXED, __HIP_MEMORY_SCOPE_AGENT);
      const size_t ix = ((size_t)b * NT + t) * ND + e0;
      float4 o;
      o.x = h0v * silu_f(xg4.x);
      o.y = h1v * silu_f(xg4.y);
      o.z = h2v * silu_f(xg4.z);
      o.w = h3v * silu_f(xg4.w);
      *(float4*)&outp[ix] = o;
      if (t == NT - 1) {
        float4 hf;
        hf.x = h0v; hf.y = h1v; hf.z = h2v; hf.w = h3v;
        *(float4*)&outp[(size_t)NB * NT * ND + (size_t)b * ND + e0] = hf;
      }
    }
  }
}

extern "C" void kernel_launch(void* const* d_in, const int* in_sizes, int n_in,
                              void* d_out, int out_size, void* d_ws, size_t ws_size,
                              hipStream_t stream) {
  (void)in_sizes; (void)n_in; (void)out_size; (void)ws_size;
  const float* x = (const float*)d_in[0];
  const float* h0 = (const float*)d_in[1];
  const float* Wx = (const float*)d_in[2];
  const float* Wh = (const float*)d_in[3];
  const float* bias = (const float*)d_in[4];
  float* outp = (float*)d_out;
  unsigned long long* tbuf = (unsigned long long*)d_ws; // [2][8][512] tagged u64 = 64 KB

  gemm_xw<<<dim3(2048), dim3(256), 0, stream>>>(x, Wx, bias, outp);
  init_state<<<dim3(16), dim3(256), 0, stream>>>(h0, tbuf);
  recur<<<dim3(NB * GPB), dim3(256), 0, stream>>>(x, Wh, outp, tbuf);
}

// Round 5
// 7377.508 us; speedup vs baseline: 3.2435x; 1.0960x over previous
//
#include <hip/hip_runtime.h>
#include <hip/hip_bf16.h>
#include <stdint.h>

typedef __bf16 bf16_t;
typedef bf16_t bf16x8 __attribute__((ext_vector_type(8)));
typedef float f32x4 __attribute__((ext_vector_type(4)));

#define NB 8
#define NT 4096
#define ND 1024
#define GPB 16      // WGs per batch group
#define EPW 64      // e-dims per WG
#define NWPG 512    // tagged u64 words per group (=ND/2)
#define WSTR 1032   // padded LDS row stride for W staging (bf16 elems)

__device__ __forceinline__ float fast_tanh(float p) {
  return 1.0f - 2.0f / (__expf(2.0f * p) + 1.0f);
}
__device__ __forceinline__ float silu_f(float v) {
  return v / (1.0f + __expf(-v));
}
__device__ __forceinline__ unsigned short f2bf(float f) {
  bf16_t h = (bf16_t)f;
  return __builtin_bit_cast(unsigned short, h);
}
__device__ __forceinline__ bf16x8 pack8(float4 a, float4 b) {
  bf16x8 v;
  v[0] = (bf16_t)a.x; v[1] = (bf16_t)a.y; v[2] = (bf16_t)a.z; v[3] = (bf16_t)a.w;
  v[4] = (bf16_t)b.x; v[5] = (bf16_t)b.y; v[6] = (bf16_t)b.z; v[7] = (bf16_t)b.w;
  return v;
}

// ---------------- GEMM: xw[b*T+t][e] = sum_d x[.][d] * Wx[e][d] + bias[e] ----------------
__global__ __launch_bounds__(256) void gemm_xw(const float* __restrict__ x,
                                               const float* __restrict__ Wx,
                                               const float* __restrict__ bias,
                                               float* __restrict__ xw) {
  __shared__ bf16_t As[128][40];
  __shared__ bf16_t Bs[128][40];
  const int tid = threadIdx.x;
  const int bm = blockIdx.x >> 3;
  const int bn = blockIdx.x & 7;
  const int lane = tid & 63;
  const int w = tid >> 6;
  const int wm = (w >> 1) * 64;
  const int wn = (w & 1) * 64;
  const int fr = lane & 15;
  const int fg = lane >> 4;

  f32x4 zero4 = {0.f, 0.f, 0.f, 0.f};
  f32x4 acc[4][4];
#pragma unroll
  for (int i = 0; i < 4; ++i)
#pragma unroll
    for (int j = 0; j < 4; ++j) acc[i][j] = zero4;

  const int r = tid >> 1;
  const int sseg = (tid & 1) * 16;
  const float* ap = x + (size_t)(bm * 128 + r) * ND + sseg;
  const float* bp = Wx + (size_t)(bn * 128 + r) * ND + sseg;

  float4 a0 = *(const float4*)(ap + 0);
  float4 a1 = *(const float4*)(ap + 4);
  float4 a2 = *(const float4*)(ap + 8);
  float4 a3 = *(const float4*)(ap + 12);
  float4 b0 = *(const float4*)(bp + 0);
  float4 b1 = *(const float4*)(bp + 4);
  float4 b2 = *(const float4*)(bp + 8);
  float4 b3 = *(const float4*)(bp + 12);

  for (int kb = 0; kb < 32; ++kb) {
    __syncthreads();
    *(bf16x8*)&As[r][sseg] = pack8(a0, a1);
    *(bf16x8*)&As[r][sseg + 8] = pack8(a2, a3);
    *(bf16x8*)&Bs[r][sseg] = pack8(b0, b1);
    *(bf16x8*)&Bs[r][sseg + 8] = pack8(b2, b3);
    __syncthreads();
    if (kb < 31) {
      const float* ap2 = ap + (kb + 1) * 32;
      const float* bp2 = bp + (kb + 1) * 32;
      a0 = *(const float4*)(ap2 + 0);
      a1 = *(const float4*)(ap2 + 4);
      a2 = *(const float4*)(ap2 + 8);
      a3 = *(const float4*)(ap2 + 12);
      b0 = *(const float4*)(bp2 + 0);
      b1 = *(const float4*)(bp2 + 4);
      b2 = *(const float4*)(bp2 + 8);
      b3 = *(const float4*)(bp2 + 12);
    }
    bf16x8 af[4], bfv[4];
#pragma unroll
    for (int mi = 0; mi < 4; ++mi) af[mi] = *(const bf16x8*)&As[wm + mi * 16 + fr][fg * 8];
#pragma unroll
    for (int ni = 0; ni < 4; ++ni) bfv[ni] = *(const bf16x8*)&Bs[wn + ni * 16 + fr][fg * 8];
#pragma unroll
    for (int mi = 0; mi < 4; ++mi)
#pragma unroll
      for (int ni = 0; ni < 4; ++ni)
        acc[mi][ni] = __builtin_amdgcn_mfma_f32_16x16x32_bf16(af[mi], bfv[ni], acc[mi][ni], 0, 0, 0);
  }

#pragma unroll
  for (int ni = 0; ni < 4; ++ni) {
    const int col = bn * 128 + wn + ni * 16 + fr;
    const float bb = bias[col];
#pragma unroll
    for (int mi = 0; mi < 4; ++mi) {
#pragma unroll
      for (int j = 0; j < 4; ++j) {
        const int row = bm * 128 + wm + mi * 16 + fg * 4 + j;
        xw[(size_t)row * ND + col] = acc[mi][ni][j] + bb;
      }
    }
  }
}

// ---------------- init: parity-0 tagged words = {tag 0, bf16(h0) pair} ----------------
__global__ void init_state(const float* __restrict__ h0,
                           unsigned long long* __restrict__ tbuf) {
  const int i = blockIdx.x * 256 + threadIdx.x; // 4096 words
  const int b = i >> 9;
  const int j = i & 511;
  const float2 hv = *(const float2*)&h0[b * ND + 2 * j];
  const unsigned hu = (unsigned)f2bf(hv.x) | ((unsigned)f2bf(hv.y) << 16);
  __hip_atomic_store(&tbuf[i], (unsigned long long)hu, __ATOMIC_RELAXED, __HIP_MEMORY_SCOPE_AGENT);
}

// ---------------- recurrence: 8 batch groups x 16 WGs; W fragments in VGPRs ----------------
__global__ __launch_bounds__(256, 1) void recur(const float* __restrict__ x,
                                                const float* __restrict__ Wh,
                                                float* __restrict__ outp,
                                                unsigned long long* __restrict__ tbuf) {
  __shared__ bf16_t W_s[EPW][WSTR]; // 132 KB: staging only (dead after frag hoist)
  __shared__ bf16_t h_s[2][ND];     // 4 KB: double-buffered h for this batch

  const int tid = threadIdx.x;
  const int wg = blockIdx.x;
  const int b = wg >> 4;
  const int wgl = wg & 15;
  const int e_base = wgl * EPW;
  const int lane = tid & 63;
  const int w = tid >> 6;
  const int fr = lane & 15;
  const int fg = lane >> 4;
  const int e0 = e_base + w * 16 + fg * 4; // this lane's 4 e-dims (used when fr==0)

  { // load W_h rows [e_base, e_base+64) as bf16 into LDS (coalesced, one-time)
    const int r = tid >> 2;
    const int c0 = (tid & 3) * 256;
    const float* wp = Wh + (size_t)(e_base + r) * ND + c0;
#pragma unroll
    for (int c = 0; c < 256; c += 8) {
      float4 v0 = *(const float4*)(wp + c);
      float4 v1 = *(const float4*)(wp + c + 4);
      *(bf16x8*)&W_s[r][c0 + c] = pack8(v0, v1);
    }
  }
  __syncthreads();
  // hoist this lane's 32 W fragments into registers (static indices -> VGPRs)
  bf16x8 wf[8][4];
  {
    const bf16_t* wrow = &W_s[w * 16 + fr][0];
#pragma unroll
    for (int cc = 0; cc < 8; ++cc)
#pragma unroll
      for (int q = 0; q < 4; ++q)
        wf[cc][q] = *(const bf16x8*)(wrow + cc * 128 + q * 32 + fg * 8);
  }

  unsigned long long* const gbase = tbuf + (size_t)b * NWPG;

  for (int t = 0; t < NT; ++t) {
    float4 xw4, xg4;
    if (fr == 0) { // prefetch this step's xw and gate input; hides under poll
      const size_t ix = ((size_t)b * NT + t) * ND + e0;
      xw4 = *(const float4*)&outp[ix];
      xg4 = *(const float4*)&x[ix];
    }
    { // poll 2 tagged words, stage into h_s[t&1]
      const unsigned long long* rbuf = gbase + (size_t)(t & 1) * (NB * NWPG);
      unsigned long long w0, w1;
      for (;;) {
        w0 = __hip_atomic_load(&rbuf[2 * tid], __ATOMIC_RELAXED, __HIP_MEMORY_SCOPE_AGENT);
        w1 = __hip_atomic_load(&rbuf[2 * tid + 1], __ATOMIC_RELAXED, __HIP_MEMORY_SCOPE_AGENT);
        if (((unsigned)(w0 >> 32) == (unsigned)t) & ((unsigned)(w1 >> 32) == (unsigned)t)) break;
      }
      const unsigned long long hv = (w0 & 0xffffffffull) | (w1 << 32);
      *(unsigned long long*)&h_s[t & 1][4 * tid] = hv;
    }
    __syncthreads(); // stage complete -> MFMA may read
    const bf16_t* hp = &h_s[t & 1][0];
    f32x4 a0 = {0.f, 0.f, 0.f, 0.f}, a1 = a0, a2 = a0, a3 = a0;
#pragma unroll
    for (int cc = 0; cc < 8; ++cc) {
      const int k = cc * 128 + fg * 8;
      a0 = __builtin_amdgcn_mfma_f32_16x16x32_bf16(wf[cc][0], *(const bf16x8*)(hp + k), a0, 0, 0, 0);
      a1 = __builtin_amdgcn_mfma_f32_16x16x32_bf16(wf[cc][1], *(const bf16x8*)(hp + k + 32), a1, 0, 0, 0);
      a2 = __builtin_amdgcn_mfma_f32_16x16x32_bf16(wf[cc][2], *(const bf16x8*)(hp + k + 64), a2, 0, 0, 0);
      a3 = __builtin_amdgcn_mfma_f32_16x16x32_bf16(wf[cc][3], *(const bf16x8*)(hp + k + 96), a3, 0, 0, 0);
    }
    const f32x4 as = (a0 + a1) + (a2 + a3); // all 16 C-columns identical; lane's 4 e-dims

    if (fr == 0) { // epilogue: publish as early as possible, then gate/store
      unsigned long long* wb = gbase + (size_t)((t + 1) & 1) * (NB * NWPG);
      const unsigned long long tag = (unsigned long long)(unsigned)(t + 1) << 32;
      const int j0 = e0 >> 1;
      const float h0v = fast_tanh(as[0] + xw4.x);
      const float h1v = fast_tanh(as[1] + xw4.y);
      const unsigned long long p0 =
          tag | (unsigned long long)((unsigned)f2bf(h0v) | ((unsigned)f2bf(h1v) << 16));
      __hip_atomic_store(&wb[j0], p0, __ATOMIC_RELAXED, __HIP_MEMORY_SCOPE_AGENT);
      const float h2v = fast_tanh(as[2] + xw4.z);
      const float h3v = fast_tanh(as[3] + xw4.w);
      const unsigned long long p1 =
          tag | (unsigned long long)((unsigned)f2bf(h2v) | ((unsigned)f2bf(h3v) << 16));
      __hip_atomic_store(&wb[j0 + 1], p1, __ATOMIC_RELAXED, __HIP_MEMORY_SCOPE_AGENT);
      const size_t ix = ((size_t)b * NT + t) * ND + e0;
      float4 o;
      o.x = h0v * silu_f(xg4.x);
      o.y = h1v * silu_f(xg4.y);
      o.z = h2v * silu_f(xg4.z);
      o.w = h3v * silu_f(xg4.w);
      *(float4*)&outp[ix] = o;
      if (t == NT - 1) {
        float4 hf;
        hf.x = h0v; hf.y = h1v; hf.z = h2v; hf.w = h3v;
        *(float4*)&outp[(size_t)NB * NT * ND + (size_t)b * ND + e0] = hf;
      }
    }
  }
}

extern "C" void kernel_launch(void* const* d_in, const int* in_sizes, int n_in,
                              void* d_out, int out_size, void* d_ws, size_t ws_size,
                              hipStream_t stream) {
  (void)in_sizes; (void)n_in; (void)out_size; (void)ws_size;
  const float* x = (const float*)d_in[0];
  const float* h0 = (const float*)d_in[1];
  const float* Wx = (const float*)d_in[2];
  const float* Wh = (const float*)d_in[3];
  const float* bias = (const float*)d_in[4];
  float* outp = (float*)d_out;
  unsigned long long* tbuf = (unsigned long long*)d_ws; // [2][8][512] tagged u64 = 64 KB

  gemm_xw<<<dim3(2048), dim3(256), 0, stream>>>(x, Wx, bias, outp);
  init_state<<<dim3(16), dim3(256), 0, stream>>>(h0, tbuf);
  recur<<<dim3(NB * GPB), dim3(256), 0, stream>>>(x, Wh, outp, tbuf);
}